// Round 3
// baseline (180.134 us; speedup 1.0000x reference)
//
#include <hip/hip_runtime.h>
#include <stdint.h>

typedef float f32x4 __attribute__((ext_vector_type(4)));
typedef __bf16 bf16x8 __attribute__((ext_vector_type(8)));
typedef unsigned short ushort8 __attribute__((ext_vector_type(8)));
typedef unsigned short u16;

#define DEVINL static __device__ __forceinline__

#if __has_builtin(__builtin_amdgcn_exp2f)
#define EXP2(x) __builtin_amdgcn_exp2f(x)
#else
#define EXP2(x) exp2f(x)
#endif

// fp32 -> bf16 round-to-nearest-even (bit-level, no API dependence)
DEVINL u16 f2bf(float f) {
  unsigned int u = __float_as_uint(f);
  return (u16)((u + 0x7fffu + ((u >> 16) & 1u)) >> 16);
}

// async global->LDS, 16B per lane. LDS dest must be wave-uniform base + lane*16.
DEVINL void gload16(const void* g, void* l) {
  __builtin_amdgcn_global_load_lds((__attribute__((address_space(1))) void*)g,
                                   (__attribute__((address_space(3))) void*)l, 16, 0, 0);
}

DEVINL f32x4 mfma16(bf16x8 a, bf16x8 b, f32x4 c) {
  return __builtin_amdgcn_mfma_f32_16x16x32_bf16(a, b, c, 0, 0, 0);
}

// ---------------- cast x (fp32) -> bf16, same layout ----------------
__global__ __launch_bounds__(256) void k_cast_bf16(const float* __restrict__ in,
                                                   u16* __restrict__ out) {
  const int i = blockIdx.x * 256 + threadIdx.x;  // 8 elems per thread
  const float4* p = (const float4*)in + (size_t)i * 2;
  float4 a = p[0], b = p[1];
  ushort8 o;
  o[0] = f2bf(a.x); o[1] = f2bf(a.y); o[2] = f2bf(a.z); o[3] = f2bf(a.w);
  o[4] = f2bf(b.x); o[5] = f2bf(b.y); o[6] = f2bf(b.z); o[7] = f2bf(b.w);
  *((ushort8*)out + i) = o;
}

// ---------------- transpose-cast: in [R][C] fp32 -> out [C][R] bf16 ----------------
__global__ __launch_bounds__(256) void k_tcast(const float* __restrict__ in,
                                               u16* __restrict__ out, int R, int C) {
  __shared__ float tile[32][33];
  const int tx = threadIdx.x & 31, ty = threadIdx.x >> 5;
  const int c0 = blockIdx.x * 32, r0 = blockIdx.y * 32;
#pragma unroll
  for (int k = 0; k < 4; ++k)
    tile[ty + k * 8][tx] = in[(size_t)(r0 + ty + k * 8) * C + (c0 + tx)];
  __syncthreads();
#pragma unroll
  for (int k = 0; k < 4; ++k)
    out[(size_t)(c0 + ty + k * 8) * R + (r0 + tx)] = f2bf(tile[tx][ty + k * 8]);
}

// ---------------- V transpose: Vb [BH][T][64] -> Vt [BH][64][T] (bf16) ----------
__global__ __launch_bounds__(256) void k_vtrans(const u16* __restrict__ V,
                                                u16* __restrict__ Vt) {
  const int t = threadIdx.x;
  const size_t base = (size_t)blockIdx.y * 131072;  // 2048*64
  const int t0 = blockIdx.x * 64;
  const int d = t & 63, kg = t >> 6;  // this thread: column d, keys kg*16..kg*16+15
  ushort8 a, b;
#pragma unroll
  for (int j = 0; j < 8; ++j)
    a[j] = V[base + (size_t)(t0 + kg * 16 + j) * 64 + d];
#pragma unroll
  for (int j = 0; j < 8; ++j)
    b[j] = V[base + (size_t)(t0 + kg * 16 + 8 + j) * 64 + d];
  *(ushort8*)(Vt + base + (size_t)d * 2048 + t0 + kg * 16) = a;
  *(ushort8*)(Vt + base + (size_t)d * 2048 + t0 + kg * 16 + 8) = b;
}

// ---------------- GEMM core: 128x128 tile, BK=64, 4 waves (2x2 of 64x64) ----------
DEVINL void stage128x64(const u16* __restrict__ g, int ld, u16* lds, int t) {
#pragma unroll
  for (int i = 0; i < 4; ++i) {
    int ci = i * 256 + t;          // 1024 chunks of 16B
    int row = ci >> 3, gr = ci & 7;
    int gs = gr ^ (row & 7);       // pre-swizzled source granule
    gload16(g + (size_t)row * ld + gs * 8, lds + ci * 8);
  }
}

DEVINL void gemm_core(const u16* __restrict__ A, const u16* __restrict__ B, int Kdim,
                      u16* As, u16* Bs, int t, f32x4 acc[4][4]) {
  const int l = t & 63, lr = l & 15, lg = l >> 4;
  const int wr = t >> 7, wc = (t >> 6) & 1;
  for (int kt = 0; kt < Kdim; kt += 64) {
    __syncthreads();               // previous-iter LDS reads done
    stage128x64(A + kt, Kdim, As, t);
    stage128x64(B + kt, Kdim, Bs, t);
    __syncthreads();               // compiler drains vmcnt before barrier
#pragma unroll
    for (int ks = 0; ks < 2; ++ks) {
      bf16x8 af[4], bf[4];
#pragma unroll
      for (int mi = 0; mi < 4; ++mi) {
        int r = wr * 64 + mi * 16 + lr;
        int g = (ks * 4 + lg) ^ (r & 7);
        af[mi] = *(const bf16x8*)(As + r * 64 + g * 8);
      }
#pragma unroll
      for (int ni = 0; ni < 4; ++ni) {
        int r = wc * 64 + ni * 16 + lr;
        int g = (ks * 4 + lg) ^ (r & 7);
        bf[ni] = *(const bf16x8*)(Bs + r * 64 + g * 8);
      }
#pragma unroll
      for (int mi = 0; mi < 4; ++mi)
#pragma unroll
        for (int ni = 0; ni < 4; ++ni)
          acc[mi][ni] = mfma16(af[mi], bf[ni], acc[mi][ni]);
    }
  }
}

// ---------------- GEMM 1: qkv = xb @ W_attn + b, scatter to Q/K/V [BH][T][D] ------
// Q is pre-scaled by 0.125*log2(e) so flash softmax runs in exp2 domain.
__global__ __launch_bounds__(256) void k_gemm_qkv(const u16* __restrict__ xb,
                                                  const u16* __restrict__ WaT,
                                                  const float* __restrict__ b_attn,
                                                  u16* __restrict__ Qo,
                                                  u16* __restrict__ Ko,
                                                  u16* __restrict__ Vo) {
  __shared__ u16 As[128 * 64], Bs[128 * 64];
  const int t = threadIdx.x;
  const int m0 = blockIdx.y * 128, n0 = blockIdx.x * 128;
  f32x4 acc[4][4] = {};
  gemm_core(xb + (size_t)m0 * 1024, WaT + (size_t)n0 * 1024, 1024, As, Bs, t, acc);
  const int l = t & 63, lr = l & 15, lg = l >> 4;
  const int wr = t >> 7, wc = (t >> 6) & 1;
#pragma unroll
  for (int ni = 0; ni < 4; ++ni) {
    const int gcol = n0 + wc * 64 + ni * 16 + lr;
    const int part = gcol >> 10;               // 0=q 1=k 2=v
    const int h = (gcol & 1023) >> 6, d = gcol & 63;
    const float bias = b_attn[gcol];
    const float osc = (part == 0) ? 0.18033688f : 1.0f;  // 0.125 * log2(e)
    u16* dst = (part == 0) ? Qo : (part == 1) ? Ko : Vo;
#pragma unroll
    for (int mi = 0; mi < 4; ++mi)
#pragma unroll
      for (int r = 0; r < 4; ++r) {
        const int grow = m0 + wr * 64 + mi * 16 + lg * 4 + r;   // b*T + t
        const int bb = grow >> 11, tt = grow & 2047;
        dst[(size_t)((bb * 16 + h) * 2048 + tt) * 64 + d] =
            f2bf((acc[mi][ni][r] + bias) * osc);
      }
  }
}

// ---------------- GEMM 2: out = Y @ W_proj + b (fp32 out) ----------------
__global__ __launch_bounds__(256) void k_gemm_proj(const u16* __restrict__ Yb,
                                                   const u16* __restrict__ WpT,
                                                   const float* __restrict__ b_proj,
                                                   float* __restrict__ out) {
  __shared__ u16 As[128 * 64], Bs[128 * 64];
  const int t = threadIdx.x;
  const int m0 = blockIdx.y * 128, n0 = blockIdx.x * 128;
  f32x4 acc[4][4] = {};
  gemm_core(Yb + (size_t)m0 * 1024, WpT + (size_t)n0 * 1024, 1024, As, Bs, t, acc);
  const int l = t & 63, lr = l & 15, lg = l >> 4;
  const int wr = t >> 7, wc = (t >> 6) & 1;
#pragma unroll
  for (int ni = 0; ni < 4; ++ni) {
    const int gcol = n0 + wc * 64 + ni * 16 + lr;
    const float bias = b_proj[gcol];
#pragma unroll
    for (int mi = 0; mi < 4; ++mi)
#pragma unroll
      for (int r = 0; r < 4; ++r) {
        const int grow = m0 + wr * 64 + mi * 16 + lg * 4 + r;
        out[(size_t)grow * 1024 + gcol] = acc[mi][ni][r] + bias;
      }
  }
}

// ---------------- flash attention (causal), 1 q-tile per block, dbuf K/V ----------
// Grid: 1024 linear blocks. Custom block->(qt,bh) map exploits XCD round-robin
// (block i -> XCD i%8, CU (i/8)%32, slot i/256):
//   u=bid&255, v=bid>>8, bh=(u&7)+8v, qt=h(v,u>>3), h = {q, 31-q, (q+8)%32, 31-(q+8)%32}
// => each CU's 4 resident blocks sum to 66 iteration-units (balanced), and all 32
//    q-tiles of one bh land on ONE XCD => 512KB K/V is L2-resident.
__global__ __launch_bounds__(256) void k_flash(const u16* __restrict__ Q,
                                               const u16* __restrict__ K,
                                               const u16* __restrict__ Vt,
                                               u16* __restrict__ Y) {
  __shared__ u16 Qs[64 * 64];      // reused as Ps (wave-private rows)
  __shared__ u16 Ks[2][64 * 64];
  __shared__ u16 Vs[2][64 * 64];   // V^T tiles: [d][key]
  const int t = threadIdx.x, l = t & 63, w = t >> 6, lr = l & 15, lg = l >> 4;
  const int bid = blockIdx.x;
  const int u = bid & 255, v = bid >> 8;
  const int bh = (u & 7) + 8 * v;
  const int q0 = u >> 3;
  const int q1 = (v & 2) ? ((q0 + 8) & 31) : q0;
  const int qt = (v & 1) ? (31 - q1) : q1;
  const size_t base = (size_t)bh * 131072;   // 2048*64 (same for K and Vt)
  const int b = bh >> 4, hh = bh & 15;
  u16* Ps = Qs;

  // stage Q tile + K/V tile 0
#pragma unroll
  for (int i = 0; i < 2; ++i) {
    int ci = i * 256 + t, row = ci >> 3, g = ci & 7, gs = g ^ (row & 7);
    gload16(Q + base + (size_t)(qt * 64 + row) * 64 + gs * 8, Qs + ci * 8);
    gload16(K + base + (size_t)row * 64 + gs * 8, Ks[0] + ci * 8);
    gload16(Vt + base + (size_t)row * 2048 + gs * 8, Vs[0] + ci * 8);
  }
  __syncthreads();
  // hoist this wave's Q fragments
  bf16x8 qa0, qa1;
  {
    const int r = w * 16 + lr, g0 = lg ^ (r & 7);
    qa0 = *(const bf16x8*)(Qs + r * 64 + g0 * 8);
    qa1 = *(const bf16x8*)(Qs + r * 64 + (g0 ^ 4) * 8);
  }
  f32x4 accO[4] = {};
  float m_old[4] = {-1e30f, -1e30f, -1e30f, -1e30f};
  float l_run[4] = {0.f, 0.f, 0.f, 0.f};

  for (int kt = 0; kt <= qt; ++kt) {
    const int cur = kt & 1;
    if (kt < qt) {   // prefetch next K/V tile (async; drained at loop-end barrier)
#pragma unroll
      for (int i = 0; i < 2; ++i) {
        int ci = i * 256 + t, row = ci >> 3, g = ci & 7, gs = g ^ (row & 7);
        gload16(K + base + (size_t)((kt + 1) * 64 + row) * 64 + gs * 8,
                Ks[cur ^ 1] + ci * 8);
        gload16(Vt + base + (size_t)row * 2048 + (kt + 1) * 64 + gs * 8,
                Vs[cur ^ 1] + ci * 8);
      }
    }
    // S = Q K^T (this wave: 16 q-rows x 64 keys) — already in exp2 domain
    f32x4 sf[4] = {};
#pragma unroll
    for (int ni = 0; ni < 4; ++ni) {
      const int r2 = ni * 16 + lr, g0 = lg ^ (r2 & 7);
      bf16x8 kb0 = *(const bf16x8*)(Ks[cur] + r2 * 64 + g0 * 8);
      bf16x8 kb1 = *(const bf16x8*)(Ks[cur] + r2 * 64 + (g0 ^ 4) * 8);
      sf[ni] = mfma16(qa0, kb0, sf[ni]);
      sf[ni] = mfma16(qa1, kb1, sf[ni]);
    }
    // causal mask (diagonal tile only)
    float s[4][4];
    const int qrow0 = qt * 64 + w * 16 + lg * 4;
#pragma unroll
    for (int ni = 0; ni < 4; ++ni) {
      const int key = kt * 64 + ni * 16 + lr;
#pragma unroll
      for (int r = 0; r < 4; ++r) {
        float v2 = sf[ni][r];
        if (kt == qt && key > qrow0 + r) v2 = -1e30f;
        s[ni][r] = v2;
      }
    }
    // online softmax (rows live in 16-lane groups)
    float mt[4];
#pragma unroll
    for (int r = 0; r < 4; ++r)
      mt[r] = fmaxf(fmaxf(s[0][r], s[1][r]), fmaxf(s[2][r], s[3][r]));
#pragma unroll
    for (int off = 8; off >= 1; off >>= 1)
#pragma unroll
      for (int r = 0; r < 4; ++r) mt[r] = fmaxf(mt[r], __shfl_xor(mt[r], off));
    float mn[4];
    bool grew = false;
#pragma unroll
    for (int r = 0; r < 4; ++r) grew |= (mt[r] > m_old[r]);
    if (__any(grew)) {   // wave-uniform: rescale path
#pragma unroll
      for (int r = 0; r < 4; ++r) {
        mn[r] = fmaxf(m_old[r], mt[r]);
        float al = EXP2(m_old[r] - mn[r]);
        l_run[r] *= al;
        m_old[r] = mn[r];
#pragma unroll
        for (int oi = 0; oi < 4; ++oi) accO[oi][r] *= al;
      }
    } else {
#pragma unroll
      for (int r = 0; r < 4; ++r) mn[r] = m_old[r];
    }
    float rs[4] = {0.f, 0.f, 0.f, 0.f};
#pragma unroll
    for (int ni = 0; ni < 4; ++ni)
#pragma unroll
      for (int r = 0; r < 4; ++r) {
        float p = EXP2(s[ni][r] - mn[r]);
        rs[r] += p;
        const int prow = w * 16 + lg * 4 + r;
        const int cg = (ni * 2 + (lr >> 3)) ^ (prow & 7);   // swizzled granule
        Ps[prow * 64 + cg * 8 + (lr & 7)] = f2bf(p);
      }
#pragma unroll
    for (int off = 8; off >= 1; off >>= 1)
#pragma unroll
      for (int r = 0; r < 4; ++r) rs[r] += __shfl_xor(rs[r], off);
#pragma unroll
    for (int r = 0; r < 4; ++r) l_run[r] += rs[r];
    // O += P V  (A = P rows, B = V^T rows; both swizzle-read)
#pragma unroll
    for (int ks = 0; ks < 2; ++ks) {
      const int rp = w * 16 + lr;
      bf16x8 pa = *(const bf16x8*)(Ps + rp * 64 + (((ks * 4 + lg) ^ (rp & 7)) * 8));
#pragma unroll
      for (int oi = 0; oi < 4; ++oi) {
        const int rv = oi * 16 + lr;
        bf16x8 vb =
            *(const bf16x8*)(Vs[cur] + rv * 64 + (((ks * 4 + lg) ^ (rv & 7)) * 8));
        accO[oi] = mfma16(pa, vb, accO[oi]);
      }
    }
    __syncthreads();   // all waves done with [cur]; prefetched loads drained
  }
  // finalize: O /= l, write Y [B][T][C] bf16
#pragma unroll
  for (int r = 0; r < 4; ++r) {
    const float inv = 1.0f / l_run[r];
    const int trow = qt * 64 + w * 16 + lg * 4 + r;
#pragma unroll
    for (int oi = 0; oi < 4; ++oi) {
      const int col = hh * 64 + oi * 16 + lr;
      Y[(size_t)(b * 2048 + trow) * 1024 + col] = f2bf(accO[oi][r] * inv);
    }
  }
}

// ---------------- launch ----------------
extern "C" void kernel_launch(void* const* d_in, const int* in_sizes, int n_in,
                              void* d_out, int out_size, void* d_ws, size_t ws_size,
                              hipStream_t stream) {
  const float* x      = (const float*)d_in[0];
  const float* W_attn = (const float*)d_in[1];
  const float* b_attn = (const float*)d_in[2];
  const float* W_proj = (const float*)d_in[3];
  const float* b_proj = (const float*)d_in[4];
  float* out = (float*)d_out;

  char* ws = (char*)d_ws;              // 48 MB total
  u16* xb  = (u16*)(ws);               //  8 MB  x as bf16 [4096][1024]; later Vt
  u16* WaT = (u16*)(ws + (8u  << 20)); //  6 MB  W_attn^T bf16 [3072][1024]
  u16* WpT = (u16*)(ws + (14u << 20)); //  2 MB  W_proj^T bf16 [1024][1024]
  u16* Qb  = (u16*)(ws + (16u << 20)); //  8 MB  [B*H][T][D]  (pre-scaled)
  u16* Kb  = (u16*)(ws + (24u << 20)); //  8 MB
  u16* Vb  = (u16*)(ws + (32u << 20)); //  8 MB
  u16* Yb  = (u16*)(ws + (40u << 20)); //  8 MB  attn out bf16 [4096][1024]
  u16* Vtb = xb;                       //  reuse: xb dead after k_gemm_qkv

  k_cast_bf16<<<dim3(2048), dim3(256), 0, stream>>>(x, xb);
  k_tcast<<<dim3(96, 32), dim3(256), 0, stream>>>(W_attn, WaT, 1024, 3072);
  k_tcast<<<dim3(32, 32), dim3(256), 0, stream>>>(W_proj, WpT, 1024, 1024);
  k_gemm_qkv<<<dim3(24, 32), dim3(256), 0, stream>>>(xb, WaT, b_attn, Qb, Kb, Vb);
  k_vtrans<<<dim3(32, 32), dim3(256), 0, stream>>>(Vb, Vtb);
  k_flash<<<dim3(1024), dim3(256), 0, stream>>>(Qb, Kb, Vtb, Yb);
  k_gemm_proj<<<dim3(8, 32), dim3(256), 0, stream>>>(Yb, WpT, b_proj, out);
}

// Round 4
// 157.370 us; speedup vs baseline: 1.1447x; 1.1447x over previous
//
#include <hip/hip_runtime.h>
#include <stdint.h>

typedef float f32x4 __attribute__((ext_vector_type(4)));
typedef __bf16 bf16x8 __attribute__((ext_vector_type(8)));
typedef unsigned short ushort8 __attribute__((ext_vector_type(8)));
typedef unsigned short u16;

#define DEVINL static __device__ __forceinline__

#if __has_builtin(__builtin_amdgcn_exp2f)
#define EXP2(x) __builtin_amdgcn_exp2f(x)
#else
#define EXP2(x) exp2f(x)
#endif

// fp32 -> bf16 via native convert (RNE; compiler packs to v_cvt_pk_bf16_f32)
DEVINL u16 f2bf(float f) {
  __bf16 h = (__bf16)f;
  return __builtin_bit_cast(u16, h);
}

// async global->LDS, 16B per lane. LDS dest must be wave-uniform base + lane*16.
DEVINL void gload16(const void* g, void* l) {
  __builtin_amdgcn_global_load_lds((__attribute__((address_space(1))) void*)g,
                                   (__attribute__((address_space(3))) void*)l, 16, 0, 0);
}

DEVINL f32x4 mfma16(bf16x8 a, bf16x8 b, f32x4 c) {
  return __builtin_amdgcn_mfma_f32_16x16x32_bf16(a, b, c, 0, 0, 0);
}

// ---------------- cast x (fp32) -> bf16, same layout ----------------
__global__ __launch_bounds__(256) void k_cast_bf16(const float* __restrict__ in,
                                                   u16* __restrict__ out) {
  const int i = blockIdx.x * 256 + threadIdx.x;  // 8 elems per thread
  const float4* p = (const float4*)in + (size_t)i * 2;
  float4 a = p[0], b = p[1];
  ushort8 o;
  o[0] = f2bf(a.x); o[1] = f2bf(a.y); o[2] = f2bf(a.z); o[3] = f2bf(a.w);
  o[4] = f2bf(b.x); o[5] = f2bf(b.y); o[6] = f2bf(b.z); o[7] = f2bf(b.w);
  *((ushort8*)out + i) = o;
}

// ---------------- transpose-cast: in [R][C] fp32 -> out [C][R] bf16 ----------------
__global__ __launch_bounds__(256) void k_tcast(const float* __restrict__ in,
                                               u16* __restrict__ out, int R, int C) {
  __shared__ float tile[32][33];
  const int tx = threadIdx.x & 31, ty = threadIdx.x >> 5;
  const int c0 = blockIdx.x * 32, r0 = blockIdx.y * 32;
#pragma unroll
  for (int k = 0; k < 4; ++k)
    tile[ty + k * 8][tx] = in[(size_t)(r0 + ty + k * 8) * C + (c0 + tx)];
  __syncthreads();
#pragma unroll
  for (int k = 0; k < 4; ++k)
    out[(size_t)(c0 + ty + k * 8) * R + (r0 + tx)] = f2bf(tile[tx][ty + k * 8]);
}

// ---------------- V transpose: Vb [BH][T][64] -> Vt [BH][64][T] (bf16) ----------
__global__ __launch_bounds__(256) void k_vtrans(const u16* __restrict__ V,
                                                u16* __restrict__ Vt) {
  const int t = threadIdx.x;
  const size_t base = (size_t)blockIdx.y * 131072;  // 2048*64
  const int t0 = blockIdx.x * 64;
  const int d = t & 63, kg = t >> 6;  // this thread: column d, keys kg*16..kg*16+15
  ushort8 a, b;
#pragma unroll
  for (int j = 0; j < 8; ++j)
    a[j] = V[base + (size_t)(t0 + kg * 16 + j) * 64 + d];
#pragma unroll
  for (int j = 0; j < 8; ++j)
    b[j] = V[base + (size_t)(t0 + kg * 16 + 8 + j) * 64 + d];
  *(ushort8*)(Vt + base + (size_t)d * 2048 + t0 + kg * 16) = a;
  *(ushort8*)(Vt + base + (size_t)d * 2048 + t0 + kg * 16 + 8) = b;
}

// ---------------- GEMM core: 128x128 tile, BK=64, 4 waves (2x2 of 64x64) ----------
DEVINL void stage128x64(const u16* __restrict__ g, int ld, u16* lds, int t) {
#pragma unroll
  for (int i = 0; i < 4; ++i) {
    int ci = i * 256 + t;          // 1024 chunks of 16B
    int row = ci >> 3, gr = ci & 7;
    int gs = gr ^ (row & 7);       // pre-swizzled source granule
    gload16(g + (size_t)row * ld + gs * 8, lds + ci * 8);
  }
}

DEVINL void gemm_core(const u16* __restrict__ A, const u16* __restrict__ B, int Kdim,
                      u16* As, u16* Bs, int t, f32x4 acc[4][4]) {
  const int l = t & 63, lr = l & 15, lg = l >> 4;
  const int wr = t >> 7, wc = (t >> 6) & 1;
  for (int kt = 0; kt < Kdim; kt += 64) {
    __syncthreads();               // previous-iter LDS reads done
    stage128x64(A + kt, Kdim, As, t);
    stage128x64(B + kt, Kdim, Bs, t);
    __syncthreads();               // compiler drains vmcnt before barrier
#pragma unroll
    for (int ks = 0; ks < 2; ++ks) {
      bf16x8 af[4], bf[4];
#pragma unroll
      for (int mi = 0; mi < 4; ++mi) {
        int r = wr * 64 + mi * 16 + lr;
        int g = (ks * 4 + lg) ^ (r & 7);
        af[mi] = *(const bf16x8*)(As + r * 64 + g * 8);
      }
#pragma unroll
      for (int ni = 0; ni < 4; ++ni) {
        int r = wc * 64 + ni * 16 + lr;
        int g = (ks * 4 + lg) ^ (r & 7);
        bf[ni] = *(const bf16x8*)(Bs + r * 64 + g * 8);
      }
#pragma unroll
      for (int mi = 0; mi < 4; ++mi)
#pragma unroll
        for (int ni = 0; ni < 4; ++ni)
          acc[mi][ni] = mfma16(af[mi], bf[ni], acc[mi][ni]);
    }
  }
}

// ---------------- GEMM 1: qkv = xb @ W_attn + b, scatter to Q/K/V [BH][T][D] ------
// Q is pre-scaled by 0.125*log2(e) so flash softmax runs in exp2 domain.
__global__ __launch_bounds__(256) void k_gemm_qkv(const u16* __restrict__ xb,
                                                  const u16* __restrict__ WaT,
                                                  const float* __restrict__ b_attn,
                                                  u16* __restrict__ Qo,
                                                  u16* __restrict__ Ko,
                                                  u16* __restrict__ Vo) {
  __shared__ u16 As[128 * 64], Bs[128 * 64];
  const int t = threadIdx.x;
  const int m0 = blockIdx.y * 128, n0 = blockIdx.x * 128;
  f32x4 acc[4][4] = {};
  gemm_core(xb + (size_t)m0 * 1024, WaT + (size_t)n0 * 1024, 1024, As, Bs, t, acc);
  const int l = t & 63, lr = l & 15, lg = l >> 4;
  const int wr = t >> 7, wc = (t >> 6) & 1;
#pragma unroll
  for (int ni = 0; ni < 4; ++ni) {
    const int gcol = n0 + wc * 64 + ni * 16 + lr;
    const int part = gcol >> 10;               // 0=q 1=k 2=v
    const int h = (gcol & 1023) >> 6, d = gcol & 63;
    const float bias = b_attn[gcol];
    const float osc = (part == 0) ? 0.18033688f : 1.0f;  // 0.125 * log2(e)
    u16* dst = (part == 0) ? Qo : (part == 1) ? Ko : Vo;
#pragma unroll
    for (int mi = 0; mi < 4; ++mi)
#pragma unroll
      for (int r = 0; r < 4; ++r) {
        const int grow = m0 + wr * 64 + mi * 16 + lg * 4 + r;   // b*T + t
        const int bb = grow >> 11, tt = grow & 2047;
        dst[(size_t)((bb * 16 + h) * 2048 + tt) * 64 + d] =
            f2bf((acc[mi][ni][r] + bias) * osc);
      }
  }
}

// ---------------- GEMM 2: out = Y @ W_proj + b (fp32 out) ----------------
__global__ __launch_bounds__(256) void k_gemm_proj(const u16* __restrict__ Yb,
                                                   const u16* __restrict__ WpT,
                                                   const float* __restrict__ b_proj,
                                                   float* __restrict__ out) {
  __shared__ u16 As[128 * 64], Bs[128 * 64];
  const int t = threadIdx.x;
  const int m0 = blockIdx.y * 128, n0 = blockIdx.x * 128;
  f32x4 acc[4][4] = {};
  gemm_core(Yb + (size_t)m0 * 1024, WpT + (size_t)n0 * 1024, 1024, As, Bs, t, acc);
  const int l = t & 63, lr = l & 15, lg = l >> 4;
  const int wr = t >> 7, wc = (t >> 6) & 1;
#pragma unroll
  for (int ni = 0; ni < 4; ++ni) {
    const int gcol = n0 + wc * 64 + ni * 16 + lr;
    const float bias = b_proj[gcol];
#pragma unroll
    for (int mi = 0; mi < 4; ++mi)
#pragma unroll
      for (int r = 0; r < 4; ++r) {
        const int grow = m0 + wr * 64 + mi * 16 + lg * 4 + r;
        out[(size_t)grow * 1024 + gcol] = acc[mi][ni][r] + bias;
      }
  }
}

// ---------------- flash attention (causal), paired q-tiles, dbuf K/V ----------
// Grid: 512 linear blocks. Block weight is UNIFORM (pair {p, 31-p} = 33 KV
// iterations) so CU assignment never unbalances. XCD locality uses only the
// measured i%8 round-robin: xcd=bid&7, j=bid>>3, bh=xcd+8*(j>>4), p=j&15
// => all 16 blocks of a bh share one XCD; 4 bh x 512KB = 2MB K/V per L2.
__global__ __launch_bounds__(256) void k_flash(const u16* __restrict__ Q,
                                               const u16* __restrict__ K,
                                               const u16* __restrict__ Vt,
                                               u16* __restrict__ Y) {
  __shared__ u16 Qs[64 * 64];      // reused as Ps (wave-private rows)
  __shared__ u16 Ks[2][64 * 64];
  __shared__ u16 Vs[2][64 * 64];   // V^T tiles: [d][key]
  const int t = threadIdx.x, l = t & 63, w = t >> 6, lr = l & 15, lg = l >> 4;
  const int bid = blockIdx.x;
  const int j = bid >> 3;
  const int bh = (bid & 7) + 8 * (j >> 4);
  const int pr = j & 15;
  const size_t base = (size_t)bh * 131072;   // 2048*64 (same for K and Vt)
  const int b = bh >> 4, hh = bh & 15;
  u16* Ps = Qs;

  for (int half = 0; half < 2; ++half) {
    const int qt = half ? 31 - pr : pr;
    __syncthreads();   // LDS reuse across halves
    // stage Q tile + K/V tile 0
#pragma unroll
    for (int i = 0; i < 2; ++i) {
      int ci = i * 256 + t, row = ci >> 3, g = ci & 7, gs = g ^ (row & 7);
      gload16(Q + base + (size_t)(qt * 64 + row) * 64 + gs * 8, Qs + ci * 8);
      gload16(K + base + (size_t)row * 64 + gs * 8, Ks[0] + ci * 8);
      gload16(Vt + base + (size_t)row * 2048 + gs * 8, Vs[0] + ci * 8);
    }
    __syncthreads();
    // hoist this wave's Q fragments
    bf16x8 qa0, qa1;
    {
      const int r = w * 16 + lr, g0 = lg ^ (r & 7);
      qa0 = *(const bf16x8*)(Qs + r * 64 + g0 * 8);
      qa1 = *(const bf16x8*)(Qs + r * 64 + (g0 ^ 4) * 8);
    }
    f32x4 accO[4] = {};
    float m_old[4] = {-1e30f, -1e30f, -1e30f, -1e30f};
    float l_run[4] = {0.f, 0.f, 0.f, 0.f};

    for (int kt = 0; kt <= qt; ++kt) {
      const int cur = kt & 1;
      if (kt < qt) {   // prefetch next K/V tile (async; drained at loop-end barrier)
#pragma unroll
        for (int i = 0; i < 2; ++i) {
          int ci = i * 256 + t, row = ci >> 3, g = ci & 7, gs = g ^ (row & 7);
          gload16(K + base + (size_t)((kt + 1) * 64 + row) * 64 + gs * 8,
                  Ks[cur ^ 1] + ci * 8);
          gload16(Vt + base + (size_t)row * 2048 + (kt + 1) * 64 + gs * 8,
                  Vs[cur ^ 1] + ci * 8);
        }
      }
      // S = Q K^T (this wave: 16 q-rows x 64 keys) — already in exp2 domain
      f32x4 sf[4] = {};
#pragma unroll
      for (int ni = 0; ni < 4; ++ni) {
        const int r2 = ni * 16 + lr, g0 = lg ^ (r2 & 7);
        bf16x8 kb0 = *(const bf16x8*)(Ks[cur] + r2 * 64 + g0 * 8);
        bf16x8 kb1 = *(const bf16x8*)(Ks[cur] + r2 * 64 + (g0 ^ 4) * 8);
        sf[ni] = mfma16(qa0, kb0, sf[ni]);
        sf[ni] = mfma16(qa1, kb1, sf[ni]);
      }
      // causal mask (diagonal tile only)
      float s[4][4];
      const int qrow0 = qt * 64 + w * 16 + lg * 4;
#pragma unroll
      for (int ni = 0; ni < 4; ++ni) {
        const int key = kt * 64 + ni * 16 + lr;
#pragma unroll
        for (int r = 0; r < 4; ++r) {
          float v2 = sf[ni][r];
          if (kt == qt && key > qrow0 + r) v2 = -1e30f;
          s[ni][r] = v2;
        }
      }
      // online softmax (rows live in 16-lane groups)
      float mt[4];
#pragma unroll
      for (int r = 0; r < 4; ++r)
        mt[r] = fmaxf(fmaxf(s[0][r], s[1][r]), fmaxf(s[2][r], s[3][r]));
#pragma unroll
      for (int off = 8; off >= 1; off >>= 1)
#pragma unroll
        for (int r = 0; r < 4; ++r) mt[r] = fmaxf(mt[r], __shfl_xor(mt[r], off));
      float mn[4];
      bool grew = false;
#pragma unroll
      for (int r = 0; r < 4; ++r) grew |= (mt[r] > m_old[r]);
      if (__any(grew)) {   // wave-uniform rescale path
#pragma unroll
        for (int r = 0; r < 4; ++r) {
          mn[r] = fmaxf(m_old[r], mt[r]);
          float al = EXP2(m_old[r] - mn[r]);
          l_run[r] *= al;
          m_old[r] = mn[r];
#pragma unroll
          for (int oi = 0; oi < 4; ++oi) accO[oi][r] *= al;
        }
      } else {
#pragma unroll
        for (int r = 0; r < 4; ++r) mn[r] = m_old[r];
      }
      float rs[4] = {0.f, 0.f, 0.f, 0.f};
#pragma unroll
      for (int ni = 0; ni < 4; ++ni)
#pragma unroll
        for (int r = 0; r < 4; ++r) {
          float p = EXP2(s[ni][r] - mn[r]);
          rs[r] += p;
          const int prow = w * 16 + lg * 4 + r;
          const int cg = (ni * 2 + (lr >> 3)) ^ (prow & 7);   // swizzled granule
          Ps[prow * 64 + cg * 8 + (lr & 7)] = f2bf(p);
        }
#pragma unroll
      for (int off = 8; off >= 1; off >>= 1)
#pragma unroll
        for (int r = 0; r < 4; ++r) rs[r] += __shfl_xor(rs[r], off);
#pragma unroll
      for (int r = 0; r < 4; ++r) l_run[r] += rs[r];
      // O += P V  (A = P rows, B = V^T rows; both swizzle-read)
#pragma unroll
      for (int ks = 0; ks < 2; ++ks) {
        const int rp = w * 16 + lr;
        bf16x8 pa = *(const bf16x8*)(Ps + rp * 64 + (((ks * 4 + lg) ^ (rp & 7)) * 8));
#pragma unroll
        for (int oi = 0; oi < 4; ++oi) {
          const int rv = oi * 16 + lr;
          bf16x8 vb =
              *(const bf16x8*)(Vs[cur] + rv * 64 + (((ks * 4 + lg) ^ (rv & 7)) * 8));
          accO[oi] = mfma16(pa, vb, accO[oi]);
        }
      }
      __syncthreads();   // all waves done with [cur]; prefetched loads drained
    }
    // finalize: O /= l, write Y [B][T][C] bf16
#pragma unroll
    for (int r = 0; r < 4; ++r) {
      const float inv = 1.0f / l_run[r];
      const int trow = qt * 64 + w * 16 + lg * 4 + r;
#pragma unroll
      for (int oi = 0; oi < 4; ++oi) {
        const int col = hh * 64 + oi * 16 + lr;
        Y[(size_t)(b * 2048 + trow) * 1024 + col] = f2bf(accO[oi][r] * inv);
      }
    }
  }
}

// ---------------- launch ----------------
extern "C" void kernel_launch(void* const* d_in, const int* in_sizes, int n_in,
                              void* d_out, int out_size, void* d_ws, size_t ws_size,
                              hipStream_t stream) {
  const float* x      = (const float*)d_in[0];
  const float* W_attn = (const float*)d_in[1];
  const float* b_attn = (const float*)d_in[2];
  const float* W_proj = (const float*)d_in[3];
  const float* b_proj = (const float*)d_in[4];
  float* out = (float*)d_out;

  char* ws = (char*)d_ws;              // 48 MB total
  u16* xb  = (u16*)(ws);               //  8 MB  x as bf16 [4096][1024]; later Vt
  u16* WaT = (u16*)(ws + (8u  << 20)); //  6 MB  W_attn^T bf16 [3072][1024]
  u16* WpT = (u16*)(ws + (14u << 20)); //  2 MB  W_proj^T bf16 [1024][1024]
  u16* Qb  = (u16*)(ws + (16u << 20)); //  8 MB  [B*H][T][D]  (pre-scaled)
  u16* Kb  = (u16*)(ws + (24u << 20)); //  8 MB
  u16* Vb  = (u16*)(ws + (32u << 20)); //  8 MB
  u16* Yb  = (u16*)(ws + (40u << 20)); //  8 MB  attn out bf16 [4096][1024]
  u16* Vtb = xb;                       //  reuse: xb dead after k_gemm_qkv

  k_cast_bf16<<<dim3(2048), dim3(256), 0, stream>>>(x, xb);
  k_tcast<<<dim3(96, 32), dim3(256), 0, stream>>>(W_attn, WaT, 1024, 3072);
  k_tcast<<<dim3(32, 32), dim3(256), 0, stream>>>(W_proj, WpT, 1024, 1024);
  k_gemm_qkv<<<dim3(24, 32), dim3(256), 0, stream>>>(xb, WaT, b_attn, Qb, Kb, Vb);
  k_vtrans<<<dim3(32, 32), dim3(256), 0, stream>>>(Vb, Vtb);
  k_flash<<<dim3(512), dim3(256), 0, stream>>>(Qb, Kb, Vtb, Yb);
  k_gemm_proj<<<dim3(8, 32), dim3(256), 0, stream>>>(Yb, WpT, b_proj, out);
}

// Round 5
// 145.281 us; speedup vs baseline: 1.2399x; 1.0832x over previous
//
#include <hip/hip_runtime.h>
#include <stdint.h>

typedef float f32x4 __attribute__((ext_vector_type(4)));
typedef __bf16 bf16x8 __attribute__((ext_vector_type(8)));
typedef unsigned short ushort8 __attribute__((ext_vector_type(8)));
typedef unsigned short u16;

#define DEVINL static __device__ __forceinline__

#define EXP2(x) exp2f(x)

// fp32 -> bf16 via native convert (RNE; compiler packs to v_cvt_pk_bf16_f32)
DEVINL u16 f2bf(float f) {
  __bf16 h = (__bf16)f;
  return __builtin_bit_cast(u16, h);
}

// async global->LDS, 16B per lane. LDS dest must be wave-uniform base + lane*16.
DEVINL void gload16(const void* g, void* l) {
  __builtin_amdgcn_global_load_lds((__attribute__((address_space(1))) void*)g,
                                   (__attribute__((address_space(3))) void*)l, 16, 0, 0);
}

DEVINL f32x4 mfma16(bf16x8 a, bf16x8 b, f32x4 c) {
  return __builtin_amdgcn_mfma_f32_16x16x32_bf16(a, b, c, 0, 0, 0);
}

// ---------------- cast x (fp32) -> bf16, same layout ----------------
__global__ __launch_bounds__(256) void k_cast_bf16(const float* __restrict__ in,
                                                   u16* __restrict__ out) {
  const int i = blockIdx.x * 256 + threadIdx.x;  // 8 elems per thread
  const float4* p = (const float4*)in + (size_t)i * 2;
  float4 a = p[0], b = p[1];
  ushort8 o;
  o[0] = f2bf(a.x); o[1] = f2bf(a.y); o[2] = f2bf(a.z); o[3] = f2bf(a.w);
  o[4] = f2bf(b.x); o[5] = f2bf(b.y); o[6] = f2bf(b.z); o[7] = f2bf(b.w);
  *((ushort8*)out + i) = o;
}

// ---------------- transpose-cast: in [R][C] fp32 -> out [C][R] bf16 ----------------
__global__ __launch_bounds__(256) void k_tcast(const float* __restrict__ in,
                                               u16* __restrict__ out, int R, int C) {
  __shared__ float tile[32][33];
  const int tx = threadIdx.x & 31, ty = threadIdx.x >> 5;
  const int c0 = blockIdx.x * 32, r0 = blockIdx.y * 32;
#pragma unroll
  for (int k = 0; k < 4; ++k)
    tile[ty + k * 8][tx] = in[(size_t)(r0 + ty + k * 8) * C + (c0 + tx)];
  __syncthreads();
#pragma unroll
  for (int k = 0; k < 4; ++k)
    out[(size_t)(c0 + ty + k * 8) * R + (r0 + tx)] = f2bf(tile[tx][ty + k * 8]);
}

// ---------------- V transpose: Vb [BH][T][64] -> Vt [BH][64][T] (bf16) ----------
__global__ __launch_bounds__(256) void k_vtrans(const u16* __restrict__ V,
                                                u16* __restrict__ Vt) {
  const int t = threadIdx.x;
  const size_t base = (size_t)blockIdx.y * 131072;  // 2048*64
  const int t0 = blockIdx.x * 64;
  const int d = t & 63, kg = t >> 6;
  ushort8 a, b;
#pragma unroll
  for (int j = 0; j < 8; ++j)
    a[j] = V[base + (size_t)(t0 + kg * 16 + j) * 64 + d];
#pragma unroll
  for (int j = 0; j < 8; ++j)
    b[j] = V[base + (size_t)(t0 + kg * 16 + 8 + j) * 64 + d];
  *(ushort8*)(Vt + base + (size_t)d * 2048 + t0 + kg * 16) = a;
  *(ushort8*)(Vt + base + (size_t)d * 2048 + t0 + kg * 16 + 8) = b;
}

// ---------------- GEMM core: 128x128 tile, BK=64, 4 waves (2x2 of 64x64) ----------
DEVINL void stage128x64(const u16* __restrict__ g, int ld, u16* lds, int t) {
#pragma unroll
  for (int i = 0; i < 4; ++i) {
    int ci = i * 256 + t;
    int row = ci >> 3, gr = ci & 7;
    int gs = gr ^ (row & 7);
    gload16(g + (size_t)row * ld + gs * 8, lds + ci * 8);
  }
}

DEVINL void gemm_core(const u16* __restrict__ A, const u16* __restrict__ B, int Kdim,
                      u16* As, u16* Bs, int t, f32x4 acc[4][4]) {
  const int l = t & 63, lr = l & 15, lg = l >> 4;
  const int wr = t >> 7, wc = (t >> 6) & 1;
  for (int kt = 0; kt < Kdim; kt += 64) {
    __syncthreads();
    stage128x64(A + kt, Kdim, As, t);
    stage128x64(B + kt, Kdim, Bs, t);
    __syncthreads();
#pragma unroll
    for (int ks = 0; ks < 2; ++ks) {
      bf16x8 af[4], bf[4];
#pragma unroll
      for (int mi = 0; mi < 4; ++mi) {
        int r = wr * 64 + mi * 16 + lr;
        int g = (ks * 4 + lg) ^ (r & 7);
        af[mi] = *(const bf16x8*)(As + r * 64 + g * 8);
      }
#pragma unroll
      for (int ni = 0; ni < 4; ++ni) {
        int r = wc * 64 + ni * 16 + lr;
        int g = (ks * 4 + lg) ^ (r & 7);
        bf[ni] = *(const bf16x8*)(Bs + r * 64 + g * 8);
      }
#pragma unroll
      for (int mi = 0; mi < 4; ++mi)
#pragma unroll
        for (int ni = 0; ni < 4; ++ni)
          acc[mi][ni] = mfma16(af[mi], bf[ni], acc[mi][ni]);
    }
  }
}

// ---------------- GEMM 1: qkv = xb @ W_attn + b, scatter to Q/K/V [BH][T][D] ------
// Q is pre-scaled by 0.125*log2(e) so flash softmax runs in exp2 domain.
__global__ __launch_bounds__(256) void k_gemm_qkv(const u16* __restrict__ xb,
                                                  const u16* __restrict__ WaT,
                                                  const float* __restrict__ b_attn,
                                                  u16* __restrict__ Qo,
                                                  u16* __restrict__ Ko,
                                                  u16* __restrict__ Vo) {
  __shared__ u16 As[128 * 64], Bs[128 * 64];
  const int t = threadIdx.x;
  const int m0 = blockIdx.y * 128, n0 = blockIdx.x * 128;
  f32x4 acc[4][4] = {};
  gemm_core(xb + (size_t)m0 * 1024, WaT + (size_t)n0 * 1024, 1024, As, Bs, t, acc);
  const int l = t & 63, lr = l & 15, lg = l >> 4;
  const int wr = t >> 7, wc = (t >> 6) & 1;
#pragma unroll
  for (int ni = 0; ni < 4; ++ni) {
    const int gcol = n0 + wc * 64 + ni * 16 + lr;
    const int part = gcol >> 10;
    const int h = (gcol & 1023) >> 6, d = gcol & 63;
    const float bias = b_attn[gcol];
    const float osc = (part == 0) ? 0.18033688f : 1.0f;  // 0.125 * log2(e)
    u16* dst = (part == 0) ? Qo : (part == 1) ? Ko : Vo;
#pragma unroll
    for (int mi = 0; mi < 4; ++mi)
#pragma unroll
      for (int r = 0; r < 4; ++r) {
        const int grow = m0 + wr * 64 + mi * 16 + lg * 4 + r;
        const int bb = grow >> 11, tt = grow & 2047;
        dst[(size_t)((bb * 16 + h) * 2048 + tt) * 64 + d] =
            f2bf((acc[mi][ni][r] + bias) * osc);
      }
  }
}

// ---------------- GEMM 2: out = Y @ W_proj + b (fp32 out) ----------------
__global__ __launch_bounds__(256) void k_gemm_proj(const u16* __restrict__ Yb,
                                                   const u16* __restrict__ WpT,
                                                   const float* __restrict__ b_proj,
                                                   float* __restrict__ out) {
  __shared__ u16 As[128 * 64], Bs[128 * 64];
  const int t = threadIdx.x;
  const int m0 = blockIdx.y * 128, n0 = blockIdx.x * 128;
  f32x4 acc[4][4] = {};
  gemm_core(Yb + (size_t)m0 * 1024, WpT + (size_t)n0 * 1024, 1024, As, Bs, t, acc);
  const int l = t & 63, lr = l & 15, lg = l >> 4;
  const int wr = t >> 7, wc = (t >> 6) & 1;
#pragma unroll
  for (int ni = 0; ni < 4; ++ni) {
    const int gcol = n0 + wc * 64 + ni * 16 + lr;
    const float bias = b_proj[gcol];
#pragma unroll
    for (int mi = 0; mi < 4; ++mi)
#pragma unroll
      for (int r = 0; r < 4; ++r) {
        const int grow = m0 + wr * 64 + mi * 16 + lg * 4 + r;
        out[(size_t)grow * 1024 + gcol] = acc[mi][ni][r] + bias;
      }
  }
}

// ---------------- flash attention (causal), swapped-operand form ----------------
// Grid: 512 blocks, pairing {p, 31-p} (uniform 33 KV-iters). XCD map as round 4.
// Swapped QK^T: St = mfma(K,Q) -> lane owns q=lr; stats are per-lane scalars.
// P in wave-private LDS [16][72] (144B rows, b128-aligned, conflict-free).
// Swapped PV: O^T = mfma(V^T, P) -> accO q=lr matches stats; no broadcasts.
__global__ __launch_bounds__(256) void k_flash(const u16* __restrict__ Q,
                                               const u16* __restrict__ K,
                                               const u16* __restrict__ Vt,
                                               u16* __restrict__ Y) {
  __shared__ u16 Ks[2][64 * 64];
  __shared__ u16 Vs[2][64 * 64];   // V^T tiles: [d][key]
  __shared__ u16 Pl[4][16 * 72];   // wave-private P, padded rows (144B)
  const int t = threadIdx.x, l = t & 63, w = t >> 6, lr = l & 15, lg = l >> 4;
  const int bid = blockIdx.x;
  const int j = bid >> 3;
  const int bh = (bid & 7) + 8 * (j >> 4);
  const int pr = j & 15;
  const size_t base = (size_t)bh * 131072;
  const int b = bh >> 4, hh = bh & 15;
  u16* Pw = Pl[w];
  const int prow = lr * 72;        // u16 index of this lane's P row

  for (int half = 0; half < 2; ++half) {
    const int qt = half ? 31 - pr : pr;
    __syncthreads();   // LDS reuse across halves
    // stage K/V tile 0
#pragma unroll
    for (int i = 0; i < 2; ++i) {
      int ci = i * 256 + t, row = ci >> 3, g = ci & 7, gs = g ^ (row & 7);
      gload16(K + base + (size_t)row * 64 + gs * 8, Ks[0] + ci * 8);
      gload16(Vt + base + (size_t)row * 2048 + gs * 8, Vs[0] + ci * 8);
    }
    // Q fragments direct global->reg (B-fragment: lane = Q[q=lr][d=lg*8..+8])
    const int qrow = qt * 64 + w * 16 + lr;
    bf16x8 qf0 = *(const bf16x8*)(Q + base + (size_t)qrow * 64 + lg * 8);
    bf16x8 qf1 = *(const bf16x8*)(Q + base + (size_t)qrow * 64 + 32 + lg * 8);
    __syncthreads();

    f32x4 accO[4] = {};          // accO[oi][r] = O[q=lr][d=oi*16+lg*4+r]
    float m_old = -1e30f, l_run = 0.f;

    for (int kt = 0; kt <= qt; ++kt) {
      const int cur = kt & 1;
      if (kt < qt) {   // prefetch next K/V tile (drained at loop-end barrier)
#pragma unroll
        for (int i = 0; i < 2; ++i) {
          int ci = i * 256 + t, row = ci >> 3, g = ci & 7, gs = g ^ (row & 7);
          gload16(K + base + (size_t)((kt + 1) * 64 + row) * 64 + gs * 8,
                  Ks[cur ^ 1] + ci * 8);
          gload16(Vt + base + (size_t)row * 2048 + (kt + 1) * 64 + gs * 8,
                  Vs[cur ^ 1] + ci * 8);
        }
      }
      // S^T = mfma(K, Q): st[ni][r] = S[key=kt*64+ni*16+lg*4+r][q=lr]
      f32x4 st[4] = {};
      __builtin_amdgcn_s_setprio(1);
#pragma unroll
      for (int ni = 0; ni < 4; ++ni) {
        const int r2 = ni * 16 + lr, g0 = lg ^ (r2 & 7);
        bf16x8 kb0 = *(const bf16x8*)(Ks[cur] + r2 * 64 + g0 * 8);
        bf16x8 kb1 = *(const bf16x8*)(Ks[cur] + r2 * 64 + (g0 ^ 4) * 8);
        st[ni] = mfma16(kb0, qf0, st[ni]);
        st[ni] = mfma16(kb1, qf1, st[ni]);
      }
      __builtin_amdgcn_s_setprio(0);
      // causal mask (diagonal tile only; uniform branch)
      if (kt == qt) {
        const int ql = w * 16 + lr;
#pragma unroll
        for (int ni = 0; ni < 4; ++ni)
#pragma unroll
          for (int r = 0; r < 4; ++r)
            if (ni * 16 + lg * 4 + r > ql) st[ni][r] = -1e30f;
      }
      // row max: in-lane 16 + 2 cross-lg shfls (scalar stats, q=lr)
      float mt = fmaxf(fmaxf(fmaxf(st[0][0], st[0][1]), fmaxf(st[0][2], st[0][3])),
                       fmaxf(fmaxf(st[1][0], st[1][1]), fmaxf(st[1][2], st[1][3])));
      mt = fmaxf(mt, fmaxf(fmaxf(fmaxf(st[2][0], st[2][1]), fmaxf(st[2][2], st[2][3])),
                           fmaxf(fmaxf(st[3][0], st[3][1]), fmaxf(st[3][2], st[3][3]))));
      mt = fmaxf(mt, __shfl_xor(mt, 16));
      mt = fmaxf(mt, __shfl_xor(mt, 32));
      float mn = m_old;
      if (__any(mt > m_old)) {   // wave-uniform rescale path
        mn = fmaxf(m_old, mt);
        const float al = EXP2(m_old - mn);
        l_run *= al;
        m_old = mn;
#pragma unroll
        for (int oi = 0; oi < 4; ++oi)
#pragma unroll
          for (int r = 0; r < 4; ++r) accO[oi][r] *= al;
      }
      // exp + pack to wave-private P + row-sum
      float rs = 0.f;
#pragma unroll
      for (int ni = 0; ni < 4; ++ni) {
        float e0 = EXP2(st[ni][0] - mn), e1 = EXP2(st[ni][1] - mn);
        float e2 = EXP2(st[ni][2] - mn), e3 = EXP2(st[ni][3] - mn);
        rs += (e0 + e1) + (e2 + e3);
        ushort4 pk;
        pk.x = f2bf(e0); pk.y = f2bf(e1); pk.z = f2bf(e2); pk.w = f2bf(e3);
        *(ushort4*)(Pw + prow + ni * 16 + lg * 4) = pk;   // 8B, conflict-free
      }
      rs += __shfl_xor(rs, 16);
      rs += __shfl_xor(rs, 32);
      l_run += rs;
      // O^T += mfma(V^T, P): accO[oi] over d=oi*16+lg*4+r, q=lr
      __builtin_amdgcn_s_setprio(1);
#pragma unroll
      for (int ks = 0; ks < 2; ++ks) {
        bf16x8 pf = *(const bf16x8*)(Pw + prow + ks * 32 + lg * 8);
#pragma unroll
        for (int oi = 0; oi < 4; ++oi) {
          const int rv = oi * 16 + lr;
          bf16x8 vb =
              *(const bf16x8*)(Vs[cur] + rv * 64 + (((ks * 4 + lg) ^ (rv & 7)) * 8));
          accO[oi] = mfma16(vb, pf, accO[oi]);
        }
      }
      __builtin_amdgcn_s_setprio(0);
      __syncthreads();   // all waves done with [cur]; prefetched loads drained
    }
    // finalize: O /= l, write Y [B][T][C] bf16 (8B packed stores)
    const float inv = 1.0f / l_run;
    const int yrow = b * 2048 + qrow;
#pragma unroll
    for (int oi = 0; oi < 4; ++oi) {
      ushort4 o4;
      o4.x = f2bf(accO[oi][0] * inv);
      o4.y = f2bf(accO[oi][1] * inv);
      o4.z = f2bf(accO[oi][2] * inv);
      o4.w = f2bf(accO[oi][3] * inv);
      *(ushort4*)(Y + (size_t)yrow * 1024 + hh * 64 + oi * 16 + lg * 4) = o4;
    }
  }
}

// ---------------- launch ----------------
extern "C" void kernel_launch(void* const* d_in, const int* in_sizes, int n_in,
                              void* d_out, int out_size, void* d_ws, size_t ws_size,
                              hipStream_t stream) {
  const float* x      = (const float*)d_in[0];
  const float* W_attn = (const float*)d_in[1];
  const float* b_attn = (const float*)d_in[2];
  const float* W_proj = (const float*)d_in[3];
  const float* b_proj = (const float*)d_in[4];
  float* out = (float*)d_out;

  char* ws = (char*)d_ws;              // 48 MB total
  u16* xb  = (u16*)(ws);               //  8 MB  x as bf16; later Vt
  u16* WaT = (u16*)(ws + (8u  << 20)); //  6 MB  W_attn^T bf16
  u16* WpT = (u16*)(ws + (14u << 20)); //  2 MB  W_proj^T bf16
  u16* Qb  = (u16*)(ws + (16u << 20)); //  8 MB  [B*H][T][D]  (pre-scaled)
  u16* Kb  = (u16*)(ws + (24u << 20)); //  8 MB
  u16* Vb  = (u16*)(ws + (32u << 20)); //  8 MB
  u16* Yb  = (u16*)(ws + (40u << 20)); //  8 MB  attn out bf16
  u16* Vtb = xb;                       //  reuse: xb dead after k_gemm_qkv

  k_cast_bf16<<<dim3(2048), dim3(256), 0, stream>>>(x, xb);
  k_tcast<<<dim3(96, 32), dim3(256), 0, stream>>>(W_attn, WaT, 1024, 3072);
  k_tcast<<<dim3(32, 32), dim3(256), 0, stream>>>(W_proj, WpT, 1024, 1024);
  k_gemm_qkv<<<dim3(24, 32), dim3(256), 0, stream>>>(xb, WaT, b_attn, Qb, Kb, Vb);
  k_vtrans<<<dim3(32, 32), dim3(256), 0, stream>>>(Vb, Vtb);
  k_flash<<<dim3(512), dim3(256), 0, stream>>>(Qb, Kb, Vtb, Yb);
  k_gemm_proj<<<dim3(8, 32), dim3(256), 0, stream>>>(Yb, WpT, b_proj, out);
}

// Round 6
// 129.064 us; speedup vs baseline: 1.3957x; 1.1257x over previous
//
#include <hip/hip_runtime.h>
#include <stdint.h>

typedef float f32x4 __attribute__((ext_vector_type(4)));
typedef __bf16 bf16x8 __attribute__((ext_vector_type(8)));
typedef unsigned short ushort8 __attribute__((ext_vector_type(8)));
typedef unsigned short u16;

#define DEVINL static __device__ __forceinline__

#define EXP2(x) exp2f(x)

// fp32 -> bf16 via native convert (RNE; compiler packs to v_cvt_pk_bf16_f32)
DEVINL u16 f2bf(float f) {
  __bf16 h = (__bf16)f;
  return __builtin_bit_cast(u16, h);
}

// async global->LDS, 16B per lane. LDS dest must be wave-uniform base + lane*16.
DEVINL void gload16(const void* g, void* l) {
  __builtin_amdgcn_global_load_lds((__attribute__((address_space(1))) void*)g,
                                   (__attribute__((address_space(3))) void*)l, 16, 0, 0);
}

DEVINL f32x4 mfma16(bf16x8 a, bf16x8 b, f32x4 c) {
  return __builtin_amdgcn_mfma_f32_16x16x32_bf16(a, b, c, 0, 0, 0);
}

// ---------------- cast x (fp32) -> bf16, same layout ----------------
__global__ __launch_bounds__(256) void k_cast_bf16(const float* __restrict__ in,
                                                   u16* __restrict__ out) {
  const int i = blockIdx.x * 256 + threadIdx.x;  // 8 elems per thread
  const float4* p = (const float4*)in + (size_t)i * 2;
  float4 a = p[0], b = p[1];
  ushort8 o;
  o[0] = f2bf(a.x); o[1] = f2bf(a.y); o[2] = f2bf(a.z); o[3] = f2bf(a.w);
  o[4] = f2bf(b.x); o[5] = f2bf(b.y); o[6] = f2bf(b.z); o[7] = f2bf(b.w);
  *((ushort8*)out + i) = o;
}

// ---------------- transpose-cast: in [R][C] fp32 -> out [C][R] bf16 ----------------
__global__ __launch_bounds__(256) void k_tcast(const float* __restrict__ in,
                                               u16* __restrict__ out, int R, int C) {
  __shared__ float tile[32][33];
  const int tx = threadIdx.x & 31, ty = threadIdx.x >> 5;
  const int c0 = blockIdx.x * 32, r0 = blockIdx.y * 32;
#pragma unroll
  for (int k = 0; k < 4; ++k)
    tile[ty + k * 8][tx] = in[(size_t)(r0 + ty + k * 8) * C + (c0 + tx)];
  __syncthreads();
#pragma unroll
  for (int k = 0; k < 4; ++k)
    out[(size_t)(c0 + ty + k * 8) * R + (r0 + tx)] = f2bf(tile[tx][ty + k * 8]);
}

// ---------------- GEMM core: 128x128 tile, BK=64, 4 waves (2x2 of 64x64) ----------
DEVINL void stage128x64(const u16* __restrict__ g, int ld, u16* lds, int t) {
#pragma unroll
  for (int i = 0; i < 4; ++i) {
    int ci = i * 256 + t;
    int row = ci >> 3, gr = ci & 7;
    int gs = gr ^ (row & 7);
    gload16(g + (size_t)row * ld + gs * 8, lds + ci * 8);
  }
}

DEVINL void gemm_core(const u16* __restrict__ A, const u16* __restrict__ B, int Kdim,
                      u16* As, u16* Bs, int t, f32x4 acc[4][4]) {
  const int l = t & 63, lr = l & 15, lg = l >> 4;
  const int wr = t >> 7, wc = (t >> 6) & 1;
  for (int kt = 0; kt < Kdim; kt += 64) {
    __syncthreads();
    stage128x64(A + kt, Kdim, As, t);
    stage128x64(B + kt, Kdim, Bs, t);
    __syncthreads();
#pragma unroll
    for (int ks = 0; ks < 2; ++ks) {
      bf16x8 af[4], bf[4];
#pragma unroll
      for (int mi = 0; mi < 4; ++mi) {
        int r = wr * 64 + mi * 16 + lr;
        int g = (ks * 4 + lg) ^ (r & 7);
        af[mi] = *(const bf16x8*)(As + r * 64 + g * 8);
      }
#pragma unroll
      for (int ni = 0; ni < 4; ++ni) {
        int r = wc * 64 + ni * 16 + lr;
        int g = (ks * 4 + lg) ^ (r & 7);
        bf[ni] = *(const bf16x8*)(Bs + r * 64 + g * 8);
      }
#pragma unroll
      for (int mi = 0; mi < 4; ++mi)
#pragma unroll
        for (int ni = 0; ni < 4; ++ni)
          acc[mi][ni] = mfma16(af[mi], bf[ni], acc[mi][ni]);
    }
  }
}

// ---------------- GEMM 1: qkv = xb @ W_attn + b -> Q/K [BH][T][D], V^T [BH][D][T] --
// Q is pre-scaled by 0.125*log2(e) so flash softmax runs in exp2 domain.
__global__ __launch_bounds__(256) void k_gemm_qkv(const u16* __restrict__ xb,
                                                  const u16* __restrict__ WaT,
                                                  const float* __restrict__ b_attn,
                                                  u16* __restrict__ Qo,
                                                  u16* __restrict__ Ko,
                                                  u16* __restrict__ Vto) {
  __shared__ u16 As[128 * 64], Bs[128 * 64];
  const int t = threadIdx.x;
  const int m0 = blockIdx.y * 128, n0 = blockIdx.x * 128;
  f32x4 acc[4][4] = {};
  gemm_core(xb + (size_t)m0 * 1024, WaT + (size_t)n0 * 1024, 1024, As, Bs, t, acc);
  const int l = t & 63, lr = l & 15, lg = l >> 4;
  const int wr = t >> 7, wc = (t >> 6) & 1;
#pragma unroll
  for (int ni = 0; ni < 4; ++ni) {
    const int gcol = n0 + wc * 64 + ni * 16 + lr;
    const int part = gcol >> 10;
    const int h = (gcol & 1023) >> 6, d = gcol & 63;
    const float bias = b_attn[gcol];
    if (part == 2) {
      // V: write transposed directly -> Vt[bh][d][t] (4x ushort4 packed stores)
#pragma unroll
      for (int mi = 0; mi < 4; ++mi) {
        const int tt0 = m0 + wr * 64 + mi * 16 + lg * 4;
        const int bb = tt0 >> 11, tt = tt0 & 2047;
        ushort4 pk;
        pk.x = f2bf(acc[mi][ni][0] + bias);
        pk.y = f2bf(acc[mi][ni][1] + bias);
        pk.z = f2bf(acc[mi][ni][2] + bias);
        pk.w = f2bf(acc[mi][ni][3] + bias);
        *(ushort4*)(Vto + (size_t)(bb * 16 + h) * 131072 + (size_t)d * 2048 + tt) = pk;
      }
    } else {
      const float osc = (part == 0) ? 0.18033688f : 1.0f;  // 0.125 * log2(e)
      u16* dst = (part == 0) ? Qo : Ko;
#pragma unroll
      for (int mi = 0; mi < 4; ++mi)
#pragma unroll
        for (int r = 0; r < 4; ++r) {
          const int grow = m0 + wr * 64 + mi * 16 + lg * 4 + r;
          const int bb = grow >> 11, tt = grow & 2047;
          dst[(size_t)((bb * 16 + h) * 2048 + tt) * 64 + d] =
              f2bf((acc[mi][ni][r] + bias) * osc);
        }
    }
  }
}

// ---------------- GEMM 2: out = Y @ W_proj + b (fp32 out) ----------------
__global__ __launch_bounds__(256) void k_gemm_proj(const u16* __restrict__ Yb,
                                                   const u16* __restrict__ WpT,
                                                   const float* __restrict__ b_proj,
                                                   float* __restrict__ out) {
  __shared__ u16 As[128 * 64], Bs[128 * 64];
  const int t = threadIdx.x;
  const int m0 = blockIdx.y * 128, n0 = blockIdx.x * 128;
  f32x4 acc[4][4] = {};
  gemm_core(Yb + (size_t)m0 * 1024, WpT + (size_t)n0 * 1024, 1024, As, Bs, t, acc);
  const int l = t & 63, lr = l & 15, lg = l >> 4;
  const int wr = t >> 7, wc = (t >> 6) & 1;
#pragma unroll
  for (int ni = 0; ni < 4; ++ni) {
    const int gcol = n0 + wc * 64 + ni * 16 + lr;
    const float bias = b_proj[gcol];
#pragma unroll
    for (int mi = 0; mi < 4; ++mi)
#pragma unroll
      for (int r = 0; r < 4; ++r) {
        const int grow = m0 + wr * 64 + mi * 16 + lg * 4 + r;
        out[(size_t)grow * 1024 + gcol] = acc[mi][ni][r] + bias;
      }
  }
}

// ---------------- flash attention (causal), key-split 8-wave blocks ----------------
// Grid: 512 blocks x 512 threads. Wave w: wq=w&3 (16 q-rows), wk=w>>2 (32-key half).
// Each wave runs an independent online softmax over its key half (no per-iter
// cross-wave sync); waves (wq,0) and (wq,1) merge m/l/accO via LDS once per q-tile.
// Pairing {p, 31-p} = uniform 33 KV iters. XCD map: bid&7 (measured i%8 rule).
__global__ __launch_bounds__(512, 4) void k_flash(const u16* __restrict__ Q,
                                                  const u16* __restrict__ K,
                                                  const u16* __restrict__ Vt,
                                                  u16* __restrict__ Y) {
  __shared__ u16 Ks[2][64 * 64];
  __shared__ u16 Vs[2][64 * 64];   // V^T tiles: [d][key]
  __shared__ u16 Pl[8][16 * 40];   // per-wave P, rows padded to 80B (2-way free)
  __shared__ float Ms[4][64][20];  // merge scratch: accO[16] + m + l per lane
  const int t = threadIdx.x, l = t & 63, w = t >> 6, lr = l & 15, lg = l >> 4;
  const int wq = w & 3, wk = w >> 2;
  const int bid = blockIdx.x;
  const int j = bid >> 3;
  const int bh = (bid & 7) + 8 * (j >> 4);
  const int pr = j & 15;
  const size_t base = (size_t)bh * 131072;
  const int b = bh >> 4, hh = bh & 15;
  u16* Pw = Pl[w];
  const int prow = lr * 40;

  for (int half = 0; half < 2; ++half) {
    const int qt = half ? 31 - pr : pr;
    __syncthreads();   // LDS reuse across halves
    // stage K/V tile 0 (512 threads, one 16B chunk each per buffer)
    {
      int row = t >> 3, g = t & 7, gs = g ^ (row & 7);
      gload16(K + base + (size_t)row * 64 + gs * 8, Ks[0] + t * 8);
      gload16(Vt + base + (size_t)row * 2048 + gs * 8, Vs[0] + t * 8);
    }
    // Q fragments direct global->reg (B-fragment: lane = Q[q=lr][d=lg*8..+8])
    const int qrow = qt * 64 + wq * 16 + lr;
    bf16x8 qf0 = *(const bf16x8*)(Q + base + (size_t)qrow * 64 + lg * 8);
    bf16x8 qf1 = *(const bf16x8*)(Q + base + (size_t)qrow * 64 + 32 + lg * 8);
    __syncthreads();

    f32x4 accO[4] = {};          // accO[oi][r] = O[q=lr][d=oi*16+lg*4+r]
    float m_old = -1e30f, l_run = 0.f;

    for (int kt = 0; kt <= qt; ++kt) {
      const int cur = kt & 1;
      if (kt < qt) {   // prefetch next K/V tile (drained at loop-end barrier)
        int row = t >> 3, g = t & 7, gs = g ^ (row & 7);
        gload16(K + base + (size_t)((kt + 1) * 64 + row) * 64 + gs * 8,
                Ks[cur ^ 1] + t * 8);
        gload16(Vt + base + (size_t)row * 2048 + (kt + 1) * 64 + gs * 8,
                Vs[cur ^ 1] + t * 8);
      }
      // diagonal tile: waves whose whole key-half is masked skip compute
      const bool full_skip = (kt == qt) && (wk == 1) && (wq < 2);
      if (!full_skip) {
        // S^T = mfma(K, Q) over this wave's 32-key half
        f32x4 st[2] = {};
        __builtin_amdgcn_s_setprio(1);
#pragma unroll
        for (int ni = 0; ni < 2; ++ni) {
          const int r2 = wk * 32 + ni * 16 + lr, g0 = lg ^ (r2 & 7);
          bf16x8 kb0 = *(const bf16x8*)(Ks[cur] + r2 * 64 + g0 * 8);
          bf16x8 kb1 = *(const bf16x8*)(Ks[cur] + r2 * 64 + (g0 ^ 4) * 8);
          st[ni] = mfma16(kb0, qf0, st[ni]);
          st[ni] = mfma16(kb1, qf1, st[ni]);
        }
        __builtin_amdgcn_s_setprio(0);
        // causal mask (diagonal tile only; local coords)
        if (kt == qt) {
          const int ql = wq * 16 + lr;
#pragma unroll
          for (int ni = 0; ni < 2; ++ni)
#pragma unroll
            for (int r = 0; r < 4; ++r)
              if (wk * 32 + ni * 16 + lg * 4 + r > ql) st[ni][r] = -1e30f;
        }
        // row max: 7-op in-lane tree + 2 cross-lg shfls (q=lr scalar stats)
        float mt = fmaxf(fmaxf(fmaxf(st[0][0], st[0][1]), fmaxf(st[0][2], st[0][3])),
                         fmaxf(fmaxf(st[1][0], st[1][1]), fmaxf(st[1][2], st[1][3])));
        mt = fmaxf(mt, __shfl_xor(mt, 16));
        mt = fmaxf(mt, __shfl_xor(mt, 32));
        // defer-rescale (T13): only rescale when max grew by > 8 (P <= 2^8, safe)
        if (__any(mt > m_old + 8.0f)) {
          const float mn2 = fmaxf(m_old, mt);
          const float al = EXP2(m_old - mn2);
          l_run *= al;
          m_old = mn2;
#pragma unroll
          for (int oi = 0; oi < 4; ++oi)
#pragma unroll
            for (int r = 0; r < 4; ++r) accO[oi][r] *= al;
        }
        const float mn = m_old;
        // exp + pack to per-wave P + row-sum
        float rs = 0.f;
#pragma unroll
        for (int ni = 0; ni < 2; ++ni) {
          float e0 = EXP2(st[ni][0] - mn), e1 = EXP2(st[ni][1] - mn);
          float e2 = EXP2(st[ni][2] - mn), e3 = EXP2(st[ni][3] - mn);
          rs += (e0 + e1) + (e2 + e3);
          ushort4 pk;
          pk.x = f2bf(e0); pk.y = f2bf(e1); pk.z = f2bf(e2); pk.w = f2bf(e3);
          *(ushort4*)(Pw + prow + ni * 16 + lg * 4) = pk;
        }
        rs += __shfl_xor(rs, 16);
        rs += __shfl_xor(rs, 32);
        l_run += rs;
        // O^T += mfma(V^T, P): single 32-K step over this wave's key half
        bf16x8 pf = *(const bf16x8*)(Pw + prow + lg * 8);
        __builtin_amdgcn_s_setprio(1);
#pragma unroll
        for (int oi = 0; oi < 4; ++oi) {
          const int rv = oi * 16 + lr;
          bf16x8 vb =
              *(const bf16x8*)(Vs[cur] + rv * 64 + (((wk * 4 + lg) ^ (rv & 7)) * 8));
          accO[oi] = mfma16(vb, pf, accO[oi]);
        }
        __builtin_amdgcn_s_setprio(0);
      }
      __syncthreads();   // all waves done with [cur]; prefetched loads drained
    }
    // merge key-halves: high waves publish, low waves combine + write Y
    if (wk == 1) {
      float* Mp = Ms[wq][l];
#pragma unroll
      for (int oi = 0; oi < 4; ++oi) *(f32x4*)(Mp + oi * 4) = accO[oi];
      Mp[16] = m_old;
      Mp[17] = l_run;
    }
    __syncthreads();
    if (wk == 0) {
      const float* Mp = Ms[wq][l];
      const float pm = Mp[16], pl = Mp[17];
      const float m = fmaxf(m_old, pm);
      const float fa = EXP2(m_old - m), fb = EXP2(pm - m);
      const float inv = 1.0f / (l_run * fa + pl * fb);
      const int yrow = b * 2048 + qrow;
#pragma unroll
      for (int oi = 0; oi < 4; ++oi) {
        f32x4 po = *(const f32x4*)(Mp + oi * 4);
        ushort4 o4;
        o4.x = f2bf((accO[oi][0] * fa + po[0] * fb) * inv);
        o4.y = f2bf((accO[oi][1] * fa + po[1] * fb) * inv);
        o4.z = f2bf((accO[oi][2] * fa + po[2] * fb) * inv);
        o4.w = f2bf((accO[oi][3] * fa + po[3] * fb) * inv);
        *(ushort4*)(Y + (size_t)yrow * 1024 + hh * 64 + oi * 16 + lg * 4) = o4;
      }
    }
  }
}

// ---------------- launch ----------------
extern "C" void kernel_launch(void* const* d_in, const int* in_sizes, int n_in,
                              void* d_out, int out_size, void* d_ws, size_t ws_size,
                              hipStream_t stream) {
  const float* x      = (const float*)d_in[0];
  const float* W_attn = (const float*)d_in[1];
  const float* b_attn = (const float*)d_in[2];
  const float* W_proj = (const float*)d_in[3];
  const float* b_proj = (const float*)d_in[4];
  float* out = (float*)d_out;

  char* ws = (char*)d_ws;              // 48 MB total
  u16* xb  = (u16*)(ws);               //  8 MB  x as bf16
  u16* WaT = (u16*)(ws + (8u  << 20)); //  6 MB  W_attn^T bf16
  u16* WpT = (u16*)(ws + (14u << 20)); //  2 MB  W_proj^T bf16
  u16* Qb  = (u16*)(ws + (16u << 20)); //  8 MB  [B*H][T][D]  (pre-scaled)
  u16* Kb  = (u16*)(ws + (24u << 20)); //  8 MB
  u16* Vtb = (u16*)(ws + (32u << 20)); //  8 MB  V^T [B*H][D][T] (written by qkv)
  u16* Yb  = (u16*)(ws + (40u << 20)); //  8 MB  attn out bf16

  k_cast_bf16<<<dim3(2048), dim3(256), 0, stream>>>(x, xb);
  k_tcast<<<dim3(96, 32), dim3(256), 0, stream>>>(W_attn, WaT, 1024, 3072);
  k_tcast<<<dim3(32, 32), dim3(256), 0, stream>>>(W_proj, WpT, 1024, 1024);
  k_gemm_qkv<<<dim3(24, 32), dim3(256), 0, stream>>>(xb, WaT, b_attn, Qb, Kb, Vtb);
  k_flash<<<dim3(512), dim3(512), 0, stream>>>(Qb, Kb, Vtb, Yb);
  k_gemm_proj<<<dim3(8, 32), dim3(256), 0, stream>>>(Yb, WpT, b_proj, out);
}